// Round 7
// baseline (342.026 us; speedup 1.0000x reference)
//
#include <hip/hip_runtime.h>
#include <hip/hip_bf16.h>

// Problem constants
#define BB 2
#define SS 2048
#define DD 64
#define HH 8
#define HD 512            // HH*DD
#define SCALE 0.125f      // 1/sqrt(64)

typedef __bf16 bf16;
typedef __attribute__((ext_vector_type(4))) __bf16 bf16x4;
typedef __attribute__((ext_vector_type(8))) __bf16 bf16x8;
typedef __attribute__((ext_vector_type(4))) float floatx4;

#define PSLOT 2097152     // bf16 elements per partial slot = BB*HH*SS*DD (4 MiB)

__device__ __forceinline__ floatx4 mfma16(bf16x8 a, bf16x8 b, floatx4 c) {
    return __builtin_amdgcn_mfma_f32_16x16x32_bf16(a, b, c, 0, 0, 0);
}

// v_mfma_f32_16x16x16_bf16: A 2 VGPRs (4 bf16), B 2 VGPRs, C/D 4 VGPRs.
// NON-volatile: data-dependency ordered, compiler may schedule around it.
#define PV_MFMA(ACC, A, B) \
    asm("v_mfma_f32_16x16x16_bf16 %0, %1, %2, %0" \
        : "+v"(ACC) : "v"(A), "v"(B))

__device__ __forceinline__ bf16x8 load8(const void* base, size_t idx, int f32) {
    if (f32) {
        const float* p = (const float*)base + idx;
        const float4 a = *reinterpret_cast<const float4*>(p);
        const float4 b = *reinterpret_cast<const float4*>(p + 4);
        bf16x8 r;
        r[0] = (bf16)a.x; r[1] = (bf16)a.y; r[2] = (bf16)a.z; r[3] = (bf16)a.w;
        r[4] = (bf16)b.x; r[5] = (bf16)b.y; r[6] = (bf16)b.z; r[7] = (bf16)b.w;
        return r;
    }
    return *reinterpret_cast<const bf16x8*>((const bf16*)base + idx);
}

__device__ __forceinline__ float load1(const void* base, int idx, int f32) {
    return f32 ? ((const float*)base)[idx] : (float)((const bf16*)base)[idx];
}

// ---------------------------------------------------------------------------
// Kernel 1: QKV projection + RoPE + fp32 norms.
// Q/K use SWAPPED MFMA operands (C = W·q^T): C-frag row=quad*4+r = d_local,
// col=l16 = s_local -> each lane holds 4 consecutive d of one row s:
//   * RoPE pairs (even,odd d) are IN-LANE (regs 0/1 and 2/3) - no shuffles
//   * 8 sincos/lane (2 per t) instead of 16
//   * stores are bf16x4 into [s][d] (the layout attn's A-frags need)
//   * norm reduce: in-lane + 2 quad shuffles
// V uses unswapped orientation, stored TILE-MAJOR vt[bh][kt][d][k%16] so
// attn's PV A-frag loads are fully coalesced (512 B / instruction).
// Dtype detection inlined (bf16 N(0,1) never has exp field >= 134).
// ---------------------------------------------------------------------------
__global__ __launch_bounds__(64) void proj_rope_kernel(
    const void* __restrict__ q, const void* __restrict__ Wq,
    const void* __restrict__ Wk, const void* __restrict__ Wv,
    bf16* __restrict__ qh, bf16* __restrict__ kh, bf16* __restrict__ vt,
    float* __restrict__ qn, float* __restrict__ kn,
    int* __restrict__ flagw)
{
    const int lane = threadIdx.x;
    const int l16  = lane & 15;
    const int quad = lane >> 4;

    // inline dtype detection over q's first 1024 halfwords
    int hit = 0;
    const unsigned short* qu = (const unsigned short*)q;
#pragma unroll
    for (int i = 0; i < 16; ++i) {
        const unsigned short u = qu[lane + i * 64];
        if (((u >> 7) & 0xFF) >= 134) hit = 1;
    }
    const int f32 = (__ballot(hit) != 0ull) ? 1 : 0;
    if (blockIdx.x == 0 && lane == 0) *flagw = f32;

    int id = blockIdx.x;                 // ((w*BB + b)*(SS/16) + st)*HH + h
    const int h  = id % HH; id /= HH;
    const int st = id % (SS / 16); id /= (SS / 16);
    const int b  = id % BB; id /= BB;
    const int w  = id;                   // 0=q, 1=k, 2=v
    const int s0 = st * 16;

    const void* W = (w == 0) ? Wq : (w == 1) ? Wk : Wv;

    const size_t qrow = ((size_t)b * SS + s0 + l16) * DD;
    bf16x8 a0 = load8(q, qrow + quad * 8, f32);
    bf16x8 a1 = load8(q, qrow + quad * 8 + 32, f32);

    floatx4 cv[4];
#pragma unroll
    for (int t = 0; t < 4; ++t) {
        const size_t wrow = (size_t)(h * 64 + t * 16 + l16) * DD;
        bf16x8 b0 = load8(W, wrow + quad * 8, f32);
        bf16x8 b1 = load8(W, wrow + quad * 8 + 32, f32);
        floatx4 acc = {0.f, 0.f, 0.f, 0.f};
        if (w < 2) {            // swapped: C[m=d_local][n=s_local]
            acc = mfma16(b0, a0, acc);
            acc = mfma16(b1, a1, acc);
        } else {                // unswapped: C[m=s_local][n=d_local]... col=d
            acc = mfma16(a0, b0, acc);
            acc = mfma16(a1, b1, acc);
        }
        cv[t] = acc;
    }

    const size_t bh = (size_t)b * HH + h;

    if (w < 2) {
        bf16*  dst  = (w == 0) ? qh : kh;
        float* ndst = (w == 0) ? qn : kn;
        const float srowf = (float)(s0 + l16);
        float nacc = 0.f;
        bf16* drow = dst + (bh * SS + s0 + l16) * DD + quad * 4;
#pragma unroll
        for (int t = 0; t < 4; ++t) {
            const int dbase = t * 16 + quad * 4;      // even
            const float frevA = __builtin_amdgcn_exp2f(
                -(float)dbase * (13.2877123795f / 64.0f)) * 0.15915494309f;
            const float frevB = __builtin_amdgcn_exp2f(
                -(float)(dbase + 2) * (13.2877123795f / 64.0f)) * 0.15915494309f;
            float revA = srowf * frevA; revA -= floorf(revA);
            float revB = srowf * frevB; revB -= floorf(revB);
            const float snA = __builtin_amdgcn_sinf(revA);
            const float csA = __builtin_amdgcn_cosf(revA);
            const float snB = __builtin_amdgcn_sinf(revB);
            const float csB = __builtin_amdgcn_cosf(revB);
            const float x0 = cv[t][0], x1 = cv[t][1];
            const float x2 = cv[t][2], x3 = cv[t][3];
            const float r0 = x0 * csA - x1 * snA;
            const float r1 = x0 * snA + x1 * csA;
            const float r2 = x2 * csB - x3 * snB;
            const float r3 = x2 * snB + x3 * csB;
            nacc += r0 * r0 + r1 * r1 + r2 * r2 + r3 * r3;
            bf16x4 o; o[0]=(bf16)r0; o[1]=(bf16)r1; o[2]=(bf16)r2; o[3]=(bf16)r3;
            *reinterpret_cast<bf16x4*>(drow + t * 16) = o;
        }
        nacc += __shfl_xor(nacc, 16);
        nacc += __shfl_xor(nacc, 32);
        if (quad == 0) ndst[bh * SS + s0 + l16] = nacc;
    } else {
        // tile-major V: vt[(bh*128 + st)*1024 + d*16 + klocal]
        bf16* vrow = vt + ((size_t)bh * 128 + st) * 1024 + l16 * 16 + quad * 4;
#pragma unroll
        for (int t = 0; t < 4; ++t) {
            bf16x4 pv;
#pragma unroll
            for (int r = 0; r < 4; ++r) pv[r] = (bf16)cv[t][r];
            *reinterpret_cast<bf16x4*>(vrow + t * 256) = pv;   // d=t*16+l16
        }
    }
}

// ---------------------------------------------------------------------------
// Kernel 2: causal distance-kernel attention. Split-K (8 slots), compacted
// grid. S^T = K·Q^T via 16x16x32 MFMA; S^T C-frag (row=key, col=query) IS
// the B-frag of v_mfma_f32_16x16x16_bf16 -> exp'd scores feed PV directly
// from registers. V loads are tile-major coalesced (512 B/instruction).
// O^T = V^T·P^T in C-frags (col=query, row=d). bf16 partials.
// ---------------------------------------------------------------------------
__global__ __launch_bounds__(64, 8) void attn_kernel(
    const bf16* __restrict__ qh, const bf16* __restrict__ kh,
    const bf16* __restrict__ vt, const float* __restrict__ qn,
    const float* __restrict__ kn, const void* __restrict__ gamma,
    bf16* __restrict__ partial, const int* __restrict__ flagp,
    int ksh, int perbh)
{
    const int f32  = *flagp;
    const int lane = threadIdx.x;
    const int l16  = lane & 15;
    const int quad = lane >> 4;

    // compacted decode: group g has G qt-values x (g+1) slots, G = 2^(ksh-4)
    const int bh = blockIdx.x / perbh;
    int r = blockIdx.x - bh * perbh;
    const int G = 1 << (ksh - 4);
    int g = 0;
    while (r >= G * (g + 1)) { r -= G * (g + 1); ++g; }
    const int slot = r >> (ksh - 4);
    const int qt   = g * G + (r & (G - 1));
    const int s0   = qt * 16;
    const int tb   = slot << ksh;
    const int te   = min(tb + (1 << ksh), s0 + 16);
    const int nch  = (te - tb + 31) >> 5;           // 32-key chunks (2 tiles)
    const int h    = bh & 7;

    // p = exp2(min(-cc*raw, 0)),  cc = gamma*SCALE*log2(e) >= 0
    const float cc = load1(gamma, h, f32) * SCALE * 1.4426950408889634f;

    const bf16* qbase = qh + ((size_t)bh * SS + s0 + l16) * DD;
    bf16x8 aq0 = *reinterpret_cast<const bf16x8*>(qbase + quad * 8);
    bf16x8 aq1 = *reinterpret_cast<const bf16x8*>(qbase + quad * 8 + 32);
    const float qn_l = qn[(size_t)bh * SS + s0 + l16];

    floatx4 acc0 = {0.f,0.f,0.f,0.f}, acc1 = {0.f,0.f,0.f,0.f};
    floatx4 acc2 = {0.f,0.f,0.f,0.f}, acc3 = {0.f,0.f,0.f,0.f};

    const bf16*  kp  = kh + ((size_t)bh * SS + l16) * DD;   // + key*DD
    const float* knp = kn + (size_t)bh * SS + quad * 4;     // + key
    // tile-major V: + kt*1024 + nb*256; lane offset l16*16 + quad*4
    const bf16* vbase = vt + (size_t)bh * 131072 + l16 * 16 + quad * 4;

    // preload chunk 0 (two 16-key tiles): K frags + kn
    bf16x8 kA0 = *reinterpret_cast<const bf16x8*>(kp + (size_t)tb * DD + quad * 8);
    bf16x8 kB0 = *reinterpret_cast<const bf16x8*>(kp + (size_t)tb * DD + quad * 8 + 32);
    bf16x8 kA1 = *reinterpret_cast<const bf16x8*>(kp + (size_t)(tb + 16) * DD + quad * 8);
    bf16x8 kB1 = *reinterpret_cast<const bf16x8*>(kp + (size_t)(tb + 16) * DD + quad * 8 + 32);
    float4 knv0 = *reinterpret_cast<const float4*>(knp + tb);
    float4 knv1 = *reinterpret_cast<const float4*>(knp + tb + 16);

    int t0 = tb;
    for (int c = 0; c < nch; ++c, t0 += 32) {
        // V A-frags for both tiles (coalesced 512B per load)
        const bf16* v0p = vbase + (size_t)(t0 >> 4) * 1024;
        bf16x4 v00 = *reinterpret_cast<const bf16x4*>(v0p);
        bf16x4 v01 = *reinterpret_cast<const bf16x4*>(v0p + 256);
        bf16x4 v02 = *reinterpret_cast<const bf16x4*>(v0p + 512);
        bf16x4 v03 = *reinterpret_cast<const bf16x4*>(v0p + 768);
        bf16x4 v10 = *reinterpret_cast<const bf16x4*>(v0p + 1024);
        bf16x4 v11 = *reinterpret_cast<const bf16x4*>(v0p + 1280);
        bf16x4 v12 = *reinterpret_cast<const bf16x4*>(v0p + 1536);
        bf16x4 v13 = *reinterpret_cast<const bf16x4*>(v0p + 1792);

        // prefetch next chunk's K + kn
        bf16x8 nA0, nB0, nA1, nB1; float4 nkn0, nkn1;
        if (c + 1 < nch) {
            const int tn = t0 + 32;
            nA0 = *reinterpret_cast<const bf16x8*>(kp + (size_t)tn * DD + quad * 8);
            nB0 = *reinterpret_cast<const bf16x8*>(kp + (size_t)tn * DD + quad * 8 + 32);
            nA1 = *reinterpret_cast<const bf16x8*>(kp + (size_t)(tn + 16) * DD + quad * 8);
            nB1 = *reinterpret_cast<const bf16x8*>(kp + (size_t)(tn + 16) * DD + quad * 8 + 32);
            nkn0 = *reinterpret_cast<const float4*>(knp + tn);
            nkn1 = *reinterpret_cast<const float4*>(knp + tn + 16);
        }

        // S^T for both tiles
        floatx4 z0 = {0.f,0.f,0.f,0.f};
        z0 = mfma16(kA0, aq0, z0);
        z0 = mfma16(kB0, aq1, z0);
        floatx4 z1 = {0.f,0.f,0.f,0.f};
        z1 = mfma16(kA1, aq0, z1);
        z1 = mfma16(kB1, aq1, z1);

        bf16x4 p0, p1;
        if (t0 + 31 <= s0) {                 // both tiles fully causal
#pragma unroll
            for (int i = 0; i < 4; ++i) {
                float rawA = fmaf(-2.f, z0[i], qn_l + ((const float*)&knv0)[i]);
                float rawB = fmaf(-2.f, z1[i], qn_l + ((const float*)&knv1)[i]);
                p0[i] = (bf16)__builtin_amdgcn_exp2f(fminf(-cc * rawA, 0.f));
                p1[i] = (bf16)__builtin_amdgcn_exp2f(fminf(-cc * rawB, 0.f));
            }
        } else {                             // diagonal: key <= query mask
            const int dq0 = s0 + l16 - t0 - quad * 4;
            const int dq1 = dq0 - 16;
#pragma unroll
            for (int i = 0; i < 4; ++i) {
                float rawA = fmaf(-2.f, z0[i], qn_l + ((const float*)&knv0)[i]);
                float rawB = fmaf(-2.f, z1[i], qn_l + ((const float*)&knv1)[i]);
                float eA = __builtin_amdgcn_exp2f(fminf(-cc * rawA, 0.f));
                float eB = __builtin_amdgcn_exp2f(fminf(-cc * rawB, 0.f));
                p0[i] = (bf16)((i <= dq0) ? eA : 0.f);
                p1[i] = (bf16)((i <= dq1) ? eB : 0.f);
            }
        }

        // PV: scores feed B operand directly; V^T is A
        PV_MFMA(acc0, v00, p0);
        PV_MFMA(acc1, v01, p0);
        PV_MFMA(acc2, v02, p0);
        PV_MFMA(acc3, v03, p0);
        PV_MFMA(acc0, v10, p1);
        PV_MFMA(acc1, v11, p1);
        PV_MFMA(acc2, v12, p1);
        PV_MFMA(acc3, v13, p1);

        if (c + 1 < nch) {
            kA0 = nA0; kB0 = nB0; kA1 = nA1; kB1 = nB1;
            knv0 = nkn0; knv1 = nkn1;
        }
    }

    // cover MFMA-write -> VALU-read hazard for the asm MFMAs
    asm volatile("s_nop 7" : "+v"(acc0), "+v"(acc1), "+v"(acc2), "+v"(acc3));

    // O^T C-frag: col=query=l16, row=d_local=quad*4+r -> bf16x4 per nb
    bf16* pb = partial + (size_t)slot * PSLOT
             + ((size_t)bh * SS + s0 + l16) * DD + quad * 4;
    {
        bf16x4 o;
        o[0]=(bf16)acc0[0]; o[1]=(bf16)acc0[1]; o[2]=(bf16)acc0[2]; o[3]=(bf16)acc0[3];
        *reinterpret_cast<bf16x4*>(pb +  0) = o;
        o[0]=(bf16)acc1[0]; o[1]=(bf16)acc1[1]; o[2]=(bf16)acc1[2]; o[3]=(bf16)acc1[3];
        *reinterpret_cast<bf16x4*>(pb + 16) = o;
        o[0]=(bf16)acc2[0]; o[1]=(bf16)acc2[1]; o[2]=(bf16)acc2[2]; o[3]=(bf16)acc2[3];
        *reinterpret_cast<bf16x4*>(pb + 32) = o;
        o[0]=(bf16)acc3[0]; o[1]=(bf16)acc3[1]; o[2]=(bf16)acc3[2]; o[3]=(bf16)acc3[3];
        *reinterpret_cast<bf16x4*>(pb + 48) = o;
    }
}

// ---------------------------------------------------------------------------
// Kernel 3: fused split-K reduce + output projection. 256 threads/block;
// wave ct handles column-tile ct. NACT templated (independent slot loads).
// partial layout: [slot][bh][s][d] bf16.
// ---------------------------------------------------------------------------
template <int NACT>
__device__ __forceinline__ floatx4 opj_core(const bf16* __restrict__ partial,
                                            const void* __restrict__ Wo,
                                            int b, int srow, size_t brow,
                                            int f32, int quad) {
    floatx4 acc = {0.f, 0.f, 0.f, 0.f};
#pragma unroll 4
    for (int kk = 0; kk < HD; kk += 32) {
        const int h  = kk >> 6;
        const int d0 = (kk & 63) + quad * 8;
        const bf16* ap = partial + (((size_t)(b * 8 + h)) * SS + srow) * 64 + d0;
        bf16x8 v0 = *reinterpret_cast<const bf16x8*>(ap);
        float u[8];
#pragma unroll
        for (int i = 0; i < 8; ++i) u[i] = (float)v0[i];
#pragma unroll
        for (int s = 1; s < NACT; ++s) {
            bf16x8 vs = *reinterpret_cast<const bf16x8*>(ap + (size_t)s * PSLOT);
#pragma unroll
            for (int i = 0; i < 8; ++i) u[i] += (float)vs[i];
        }
        bf16x8 a;
#pragma unroll
        for (int i = 0; i < 8; ++i) a[i] = (bf16)u[i];
        bf16x8 w = load8(Wo, brow + kk, f32);
        acc = mfma16(a, w, acc);
    }
    return acc;
}

__global__ __launch_bounds__(256) void outproj_kernel(
    const bf16* __restrict__ partial, const void* __restrict__ Wo,
    void* __restrict__ out, const int* __restrict__ flagp, int ksh)
{
    const int f32  = *flagp;
    const int ct   = threadIdx.x >> 6;
    const int lane = threadIdx.x & 63;
    const int l16  = lane & 15;
    const int quad = lane >> 4;

    const int g0   = blockIdx.x * 16;          // global row (b*SS + s)
    const int b    = g0 >> 11;
    const int s0   = g0 & (SS - 1);
    const int nact = (s0 >> ksh) + 1;
    const int srow = s0 + l16;
    const size_t brow = (size_t)(ct * 16 + l16) * HD + quad * 8;

    floatx4 acc;
    switch (nact) {
        case 1:  acc = opj_core<1>(partial, Wo, b, srow, brow, f32, quad); break;
        case 2:  acc = opj_core<2>(partial, Wo, b, srow, brow, f32, quad); break;
        case 3:  acc = opj_core<3>(partial, Wo, b, srow, brow, f32, quad); break;
        case 4:  acc = opj_core<4>(partial, Wo, b, srow, brow, f32, quad); break;
        case 5:  acc = opj_core<5>(partial, Wo, b, srow, brow, f32, quad); break;
        case 6:  acc = opj_core<6>(partial, Wo, b, srow, brow, f32, quad); break;
        case 7:  acc = opj_core<7>(partial, Wo, b, srow, brow, f32, quad); break;
        default: acc = opj_core<8>(partial, Wo, b, srow, brow, f32, quad); break;
    }

#pragma unroll
    for (int r = 0; r < 4; ++r) {
        const size_t o = (size_t)(g0 + quad * 4 + r) * DD + ct * 16 + l16;
        if (f32) ((float*)out)[o] = acc[r];
        else     ((bf16*)out)[o]  = (bf16)acc[r];
    }
}

// ---------------------------------------------------------------------------
extern "C" void kernel_launch(void* const* d_in, const int* in_sizes, int n_in,
                              void* d_out, int out_size, void* d_ws, size_t ws_size,
                              hipStream_t stream) {
    const void* q     = d_in[0];
    const void* Wq    = d_in[1];
    const void* Wk    = d_in[2];
    const void* Wv    = d_in[3];
    const void* Wo    = d_in[4];
    const void* gamma = d_in[5];

    char* ws = (char*)d_ws;
    bf16*  qh      = (bf16*)(ws);                    // 4 MiB
    bf16*  kh      = (bf16*)(ws + 4194304);          // 4 MiB
    bf16*  vt      = (bf16*)(ws + 8388608);          // 4 MiB (tile-major)
    float* qn      = (float*)(ws + 12582912);        // 128 KiB
    float* kn      = (float*)(ws + 12713984);        // 128 KiB
    int*   flag    = (int*)  (ws + 12845056);
    bf16*  partial = (bf16*)(ws + 13631488);         // nslot x 4 MiB (bf16)

    // split-K tier by available workspace: 8 / 4 / 2 / 1 slots
    int ksh = 11;
    const size_t base = 13631488ull;
    if      (ws_size >= base + 8ull * 4194304) ksh = 8;
    else if (ws_size >= base + 4ull * 4194304) ksh = 9;
    else if (ws_size >= base + 2ull * 4194304) ksh = 10;

    const int G = 1 << (ksh - 4);
    const int n = 128 / G;                           // slot-groups
    const int perbh = G * n * (n + 1) / 2;           // active (qt,slot) per bh

    proj_rope_kernel<<<dim3(3 * BB * (SS / 16) * HH), dim3(64), 0, stream>>>(
        q, Wq, Wk, Wv, qh, kh, vt, qn, kn, flag);
    attn_kernel<<<dim3(BB * HH * perbh), dim3(64), 0, stream>>>(
        qh, kh, vt, qn, kn, gamma, partial, flag, ksh, perbh);
    outproj_kernel<<<dim3(BB * SS / 16), dim3(256), 0, stream>>>(
        partial, Wo, d_out, flag, ksh);
}

// Round 8
// 163.923 us; speedup vs baseline: 2.0865x; 2.0865x over previous
//
#include <hip/hip_runtime.h>
#include <hip/hip_bf16.h>

// Problem constants
#define BB 2
#define SS 2048
#define DD 64
#define HH 8
#define HD 512            // HH*DD
#define SCALE 0.125f      // 1/sqrt(64)

typedef __bf16 bf16;
typedef __attribute__((ext_vector_type(4))) __bf16 bf16x4;
typedef __attribute__((ext_vector_type(8))) __bf16 bf16x8;
typedef __attribute__((ext_vector_type(4))) float floatx4;

#define PSLOT 2097152     // bf16 elements per partial slot = BB*HH*SS*DD (4 MiB)

__device__ __forceinline__ floatx4 mfma16(bf16x8 a, bf16x8 b, floatx4 c) {
    return __builtin_amdgcn_mfma_f32_16x16x32_bf16(a, b, c, 0, 0, 0);
}

// v_mfma_f32_16x16x16_bf16: A 2 VGPRs (4 bf16), B 2 VGPRs, C/D 4 VGPRs.
// NON-volatile: data-dependency ordered, compiler may schedule around it.
#define PV_MFMA(ACC, A, B) \
    asm("v_mfma_f32_16x16x16_bf16 %0, %1, %2, %0" \
        : "+v"(ACC) : "v"(A), "v"(B))

__device__ __forceinline__ bf16x8 load8(const void* base, size_t idx, int f32) {
    if (f32) {
        const float* p = (const float*)base + idx;
        const float4 a = *reinterpret_cast<const float4*>(p);
        const float4 b = *reinterpret_cast<const float4*>(p + 4);
        bf16x8 r;
        r[0] = (bf16)a.x; r[1] = (bf16)a.y; r[2] = (bf16)a.z; r[3] = (bf16)a.w;
        r[4] = (bf16)b.x; r[5] = (bf16)b.y; r[6] = (bf16)b.z; r[7] = (bf16)b.w;
        return r;
    }
    return *reinterpret_cast<const bf16x8*>((const bf16*)base + idx);
}

__device__ __forceinline__ float load1(const void* base, int idx, int f32) {
    return f32 ? ((const float*)base)[idx] : (float)((const bf16*)base)[idx];
}

// ---------------------------------------------------------------------------
// Kernel 1: QKV projection + RoPE + fp32 norms.
// Q/K use SWAPPED MFMA operands (C = W·q^T): C-frag row=quad*4+r = d_local,
// col=l16 = s_local -> each lane holds 4 consecutive d of one row s:
//   * RoPE pairs (even,odd d) are IN-LANE - no shuffles
//   * 8 sincos/lane instead of 16; stores are bf16x4 into [s][d]
//   * norm reduce: in-lane + 2 quad shuffles
// V stored TILE-MAJOR vt[bh][kt][d][k%16] so attn's PV A-frag loads are
// fully coalesced (512 B / wave instruction).
// Dtype detection inlined (bf16 N(0,1) never has exp field >= 134).
// ---------------------------------------------------------------------------
__global__ __launch_bounds__(64) void proj_rope_kernel(
    const void* __restrict__ q, const void* __restrict__ Wq,
    const void* __restrict__ Wk, const void* __restrict__ Wv,
    bf16* __restrict__ qh, bf16* __restrict__ kh, bf16* __restrict__ vt,
    float* __restrict__ qn, float* __restrict__ kn,
    int* __restrict__ flagw)
{
    const int lane = threadIdx.x;
    const int l16  = lane & 15;
    const int quad = lane >> 4;

    // inline dtype detection over q's first 1024 halfwords
    int hit = 0;
    const unsigned short* qu = (const unsigned short*)q;
#pragma unroll
    for (int i = 0; i < 16; ++i) {
        const unsigned short u = qu[lane + i * 64];
        if (((u >> 7) & 0xFF) >= 134) hit = 1;
    }
    const int f32 = (__ballot(hit) != 0ull) ? 1 : 0;
    if (blockIdx.x == 0 && lane == 0) *flagw = f32;

    int id = blockIdx.x;                 // ((w*BB + b)*(SS/16) + st)*HH + h
    const int h  = id % HH; id /= HH;
    const int st = id % (SS / 16); id /= (SS / 16);
    const int b  = id % BB; id /= BB;
    const int w  = id;                   // 0=q, 1=k, 2=v
    const int s0 = st * 16;

    const void* W = (w == 0) ? Wq : (w == 1) ? Wk : Wv;

    const size_t qrow = ((size_t)b * SS + s0 + l16) * DD;
    bf16x8 a0 = load8(q, qrow + quad * 8, f32);
    bf16x8 a1 = load8(q, qrow + quad * 8 + 32, f32);

    floatx4 cv[4];
#pragma unroll
    for (int t = 0; t < 4; ++t) {
        const size_t wrow = (size_t)(h * 64 + t * 16 + l16) * DD;
        bf16x8 b0 = load8(W, wrow + quad * 8, f32);
        bf16x8 b1 = load8(W, wrow + quad * 8 + 32, f32);
        floatx4 acc = {0.f, 0.f, 0.f, 0.f};
        if (w < 2) {            // swapped: C[m=d_local][n=s_local]
            acc = mfma16(b0, a0, acc);
            acc = mfma16(b1, a1, acc);
        } else {                // unswapped: C[m=s_local][n=d_local]
            acc = mfma16(a0, b0, acc);
            acc = mfma16(a1, b1, acc);
        }
        cv[t] = acc;
    }

    const size_t bh = (size_t)b * HH + h;

    if (w < 2) {
        bf16*  dst  = (w == 0) ? qh : kh;
        float* ndst = (w == 0) ? qn : kn;
        const float srowf = (float)(s0 + l16);
        float nacc = 0.f;
        bf16* drow = dst + (bh * SS + s0 + l16) * DD + quad * 4;
#pragma unroll
        for (int t = 0; t < 4; ++t) {
            const int dbase = t * 16 + quad * 4;      // even
            const float frevA = __builtin_amdgcn_exp2f(
                -(float)dbase * (13.2877123795f / 64.0f)) * 0.15915494309f;
            const float frevB = __builtin_amdgcn_exp2f(
                -(float)(dbase + 2) * (13.2877123795f / 64.0f)) * 0.15915494309f;
            float revA = srowf * frevA; revA -= floorf(revA);
            float revB = srowf * frevB; revB -= floorf(revB);
            const float snA = __builtin_amdgcn_sinf(revA);
            const float csA = __builtin_amdgcn_cosf(revA);
            const float snB = __builtin_amdgcn_sinf(revB);
            const float csB = __builtin_amdgcn_cosf(revB);
            const float x0 = cv[t][0], x1 = cv[t][1];
            const float x2 = cv[t][2], x3 = cv[t][3];
            const float r0 = x0 * csA - x1 * snA;
            const float r1 = x0 * snA + x1 * csA;
            const float r2 = x2 * csB - x3 * snB;
            const float r3 = x2 * snB + x3 * csB;
            nacc += r0 * r0 + r1 * r1 + r2 * r2 + r3 * r3;
            bf16x4 o; o[0]=(bf16)r0; o[1]=(bf16)r1; o[2]=(bf16)r2; o[3]=(bf16)r3;
            *reinterpret_cast<bf16x4*>(drow + t * 16) = o;
        }
        nacc += __shfl_xor(nacc, 16);
        nacc += __shfl_xor(nacc, 32);
        if (quad == 0) ndst[bh * SS + s0 + l16] = nacc;
    } else {
        // tile-major V: vt[(bh*128 + st)*1024 + d*16 + klocal]
        bf16* vrow = vt + ((size_t)bh * 128 + st) * 1024 + l16 * 16 + quad * 4;
#pragma unroll
        for (int t = 0; t < 4; ++t) {
            bf16x4 pv;
#pragma unroll
            for (int r = 0; r < 4; ++r) pv[r] = (bf16)cv[t][r];
            *reinterpret_cast<bf16x4*>(vrow + t * 256) = pv;   // d=t*16+l16
        }
    }
}

// ---------------------------------------------------------------------------
// Kernel 2: causal distance-kernel attention. Split-K (8 slots), compacted
// grid. S^T = K·Q^T via 16x16x32 MFMA; S^T C-frag (row=key, col=query) IS
// the B-frag of v_mfma_f32_16x16x16_bf16 -> exp'd scores feed PV directly
// from registers. V loads are tile-major coalesced (512 B/instruction).
// O^T = V^T·P^T in C-frags (col=query, row=d). bf16 partials.
// NOTE: plain __launch_bounds__(64). Round 7's (64,8) capped VGPRs at 64
// and caused a 628 MB scratch-spill storm (WRITE_SIZE counter).
// ---------------------------------------------------------------------------
__global__ __launch_bounds__(64) void attn_kernel(
    const bf16* __restrict__ qh, const bf16* __restrict__ kh,
    const bf16* __restrict__ vt, const float* __restrict__ qn,
    const float* __restrict__ kn, const void* __restrict__ gamma,
    bf16* __restrict__ partial, const int* __restrict__ flagp,
    int ksh, int perbh)
{
    const int f32  = *flagp;
    const int lane = threadIdx.x;
    const int l16  = lane & 15;
    const int quad = lane >> 4;

    // compacted decode: group g has G qt-values x (g+1) slots, G = 2^(ksh-4)
    const int bh = blockIdx.x / perbh;
    int r = blockIdx.x - bh * perbh;
    const int G = 1 << (ksh - 4);
    int g = 0;
    while (r >= G * (g + 1)) { r -= G * (g + 1); ++g; }
    const int slot = r >> (ksh - 4);
    const int qt   = g * G + (r & (G - 1));
    const int s0   = qt * 16;
    const int tb   = slot << ksh;
    const int te   = min(tb + (1 << ksh), s0 + 16);
    const int nch  = (te - tb + 31) >> 5;           // 32-key chunks (2 tiles)
    const int h    = bh & 7;

    // p = exp2(min(-cc*raw, 0)),  cc = gamma*SCALE*log2(e) >= 0
    const float cc = load1(gamma, h, f32) * SCALE * 1.4426950408889634f;

    const bf16* qbase = qh + ((size_t)bh * SS + s0 + l16) * DD;
    bf16x8 aq0 = *reinterpret_cast<const bf16x8*>(qbase + quad * 8);
    bf16x8 aq1 = *reinterpret_cast<const bf16x8*>(qbase + quad * 8 + 32);
    const float qn_l = qn[(size_t)bh * SS + s0 + l16];

    floatx4 acc0 = {0.f,0.f,0.f,0.f}, acc1 = {0.f,0.f,0.f,0.f};
    floatx4 acc2 = {0.f,0.f,0.f,0.f}, acc3 = {0.f,0.f,0.f,0.f};

    const bf16*  kp  = kh + ((size_t)bh * SS + l16) * DD;   // + key*DD
    const float* knp = kn + (size_t)bh * SS + quad * 4;     // + key
    // tile-major V: + kt*1024 + nb*256; lane offset l16*16 + quad*4
    const bf16* vbase = vt + (size_t)bh * 131072 + l16 * 16 + quad * 4;

    // preload chunk 0 (two 16-key tiles): K frags + kn
    bf16x8 kA0 = *reinterpret_cast<const bf16x8*>(kp + (size_t)tb * DD + quad * 8);
    bf16x8 kB0 = *reinterpret_cast<const bf16x8*>(kp + (size_t)tb * DD + quad * 8 + 32);
    bf16x8 kA1 = *reinterpret_cast<const bf16x8*>(kp + (size_t)(tb + 16) * DD + quad * 8);
    bf16x8 kB1 = *reinterpret_cast<const bf16x8*>(kp + (size_t)(tb + 16) * DD + quad * 8 + 32);
    float4 knv0 = *reinterpret_cast<const float4*>(knp + tb);
    float4 knv1 = *reinterpret_cast<const float4*>(knp + tb + 16);

    int t0 = tb;
    for (int c = 0; c < nch; ++c, t0 += 32) {
        // V A-frags for both tiles (coalesced 512B per load)
        const bf16* v0p = vbase + (size_t)(t0 >> 4) * 1024;
        bf16x4 v00 = *reinterpret_cast<const bf16x4*>(v0p);
        bf16x4 v01 = *reinterpret_cast<const bf16x4*>(v0p + 256);
        bf16x4 v02 = *reinterpret_cast<const bf16x4*>(v0p + 512);
        bf16x4 v03 = *reinterpret_cast<const bf16x4*>(v0p + 768);
        bf16x4 v10 = *reinterpret_cast<const bf16x4*>(v0p + 1024);
        bf16x4 v11 = *reinterpret_cast<const bf16x4*>(v0p + 1280);
        bf16x4 v12 = *reinterpret_cast<const bf16x4*>(v0p + 1536);
        bf16x4 v13 = *reinterpret_cast<const bf16x4*>(v0p + 1792);

        // prefetch next chunk's K + kn
        bf16x8 nA0, nB0, nA1, nB1; float4 nkn0, nkn1;
        if (c + 1 < nch) {
            const int tn = t0 + 32;
            nA0 = *reinterpret_cast<const bf16x8*>(kp + (size_t)tn * DD + quad * 8);
            nB0 = *reinterpret_cast<const bf16x8*>(kp + (size_t)tn * DD + quad * 8 + 32);
            nA1 = *reinterpret_cast<const bf16x8*>(kp + (size_t)(tn + 16) * DD + quad * 8);
            nB1 = *reinterpret_cast<const bf16x8*>(kp + (size_t)(tn + 16) * DD + quad * 8 + 32);
            nkn0 = *reinterpret_cast<const float4*>(knp + tn);
            nkn1 = *reinterpret_cast<const float4*>(knp + tn + 16);
        }

        // S^T for both tiles
        floatx4 z0 = {0.f,0.f,0.f,0.f};
        z0 = mfma16(kA0, aq0, z0);
        z0 = mfma16(kB0, aq1, z0);
        floatx4 z1 = {0.f,0.f,0.f,0.f};
        z1 = mfma16(kA1, aq0, z1);
        z1 = mfma16(kB1, aq1, z1);

        bf16x4 p0, p1;
        if (t0 + 31 <= s0) {                 // both tiles fully causal
#pragma unroll
            for (int i = 0; i < 4; ++i) {
                float rawA = fmaf(-2.f, z0[i], qn_l + ((const float*)&knv0)[i]);
                float rawB = fmaf(-2.f, z1[i], qn_l + ((const float*)&knv1)[i]);
                p0[i] = (bf16)__builtin_amdgcn_exp2f(fminf(-cc * rawA, 0.f));
                p1[i] = (bf16)__builtin_amdgcn_exp2f(fminf(-cc * rawB, 0.f));
            }
        } else {                             // diagonal: key <= query mask
            const int dq0 = s0 + l16 - t0 - quad * 4;
            const int dq1 = dq0 - 16;
#pragma unroll
            for (int i = 0; i < 4; ++i) {
                float rawA = fmaf(-2.f, z0[i], qn_l + ((const float*)&knv0)[i]);
                float rawB = fmaf(-2.f, z1[i], qn_l + ((const float*)&knv1)[i]);
                float eA = __builtin_amdgcn_exp2f(fminf(-cc * rawA, 0.f));
                float eB = __builtin_amdgcn_exp2f(fminf(-cc * rawB, 0.f));
                p0[i] = (bf16)((i <= dq0) ? eA : 0.f);
                p1[i] = (bf16)((i <= dq1) ? eB : 0.f);
            }
        }

        // PV: scores feed B operand directly; V^T is A
        PV_MFMA(acc0, v00, p0);
        PV_MFMA(acc1, v01, p0);
        PV_MFMA(acc2, v02, p0);
        PV_MFMA(acc3, v03, p0);
        PV_MFMA(acc0, v10, p1);
        PV_MFMA(acc1, v11, p1);
        PV_MFMA(acc2, v12, p1);
        PV_MFMA(acc3, v13, p1);

        if (c + 1 < nch) {
            kA0 = nA0; kB0 = nB0; kA1 = nA1; kB1 = nB1;
            knv0 = nkn0; knv1 = nkn1;
        }
    }

    // cover MFMA-write -> VALU-read hazard for the asm MFMAs
    asm volatile("s_nop 7" : "+v"(acc0), "+v"(acc1), "+v"(acc2), "+v"(acc3));

    // O^T C-frag: col=query=l16, row=d_local=quad*4+r -> bf16x4 per nb
    bf16* pb = partial + (size_t)slot * PSLOT
             + ((size_t)bh * SS + s0 + l16) * DD + quad * 4;
    {
        bf16x4 o;
        o[0]=(bf16)acc0[0]; o[1]=(bf16)acc0[1]; o[2]=(bf16)acc0[2]; o[3]=(bf16)acc0[3];
        *reinterpret_cast<bf16x4*>(pb +  0) = o;
        o[0]=(bf16)acc1[0]; o[1]=(bf16)acc1[1]; o[2]=(bf16)acc1[2]; o[3]=(bf16)acc1[3];
        *reinterpret_cast<bf16x4*>(pb + 16) = o;
        o[0]=(bf16)acc2[0]; o[1]=(bf16)acc2[1]; o[2]=(bf16)acc2[2]; o[3]=(bf16)acc2[3];
        *reinterpret_cast<bf16x4*>(pb + 32) = o;
        o[0]=(bf16)acc3[0]; o[1]=(bf16)acc3[1]; o[2]=(bf16)acc3[2]; o[3]=(bf16)acc3[3];
        *reinterpret_cast<bf16x4*>(pb + 48) = o;
    }
}

// ---------------------------------------------------------------------------
// Kernel 3: fused split-K reduce + output projection. 256 threads/block;
// wave ct handles column-tile ct. NACT templated (independent slot loads).
// partial layout: [slot][bh][s][d] bf16.
// ---------------------------------------------------------------------------
template <int NACT>
__device__ __forceinline__ floatx4 opj_core(const bf16* __restrict__ partial,
                                            const void* __restrict__ Wo,
                                            int b, int srow, size_t brow,
                                            int f32, int quad) {
    floatx4 acc = {0.f, 0.f, 0.f, 0.f};
#pragma unroll 4
    for (int kk = 0; kk < HD; kk += 32) {
        const int h  = kk >> 6;
        const int d0 = (kk & 63) + quad * 8;
        const bf16* ap = partial + (((size_t)(b * 8 + h)) * SS + srow) * 64 + d0;
        bf16x8 v0 = *reinterpret_cast<const bf16x8*>(ap);
        float u[8];
#pragma unroll
        for (int i = 0; i < 8; ++i) u[i] = (float)v0[i];
#pragma unroll
        for (int s = 1; s < NACT; ++s) {
            bf16x8 vs = *reinterpret_cast<const bf16x8*>(ap + (size_t)s * PSLOT);
#pragma unroll
            for (int i = 0; i < 8; ++i) u[i] += (float)vs[i];
        }
        bf16x8 a;
#pragma unroll
        for (int i = 0; i < 8; ++i) a[i] = (bf16)u[i];
        bf16x8 w = load8(Wo, brow + kk, f32);
        acc = mfma16(a, w, acc);
    }
    return acc;
}

__global__ __launch_bounds__(256) void outproj_kernel(
    const bf16* __restrict__ partial, const void* __restrict__ Wo,
    void* __restrict__ out, const int* __restrict__ flagp, int ksh)
{
    const int f32  = *flagp;
    const int ct   = threadIdx.x >> 6;
    const int lane = threadIdx.x & 63;
    const int l16  = lane & 15;
    const int quad = lane >> 4;

    const int g0   = blockIdx.x * 16;          // global row (b*SS + s)
    const int b    = g0 >> 11;
    const int s0   = g0 & (SS - 1);
    const int nact = (s0 >> ksh) + 1;
    const int srow = s0 + l16;
    const size_t brow = (size_t)(ct * 16 + l16) * HD + quad * 8;

    floatx4 acc;
    switch (nact) {
        case 1:  acc = opj_core<1>(partial, Wo, b, srow, brow, f32, quad); break;
        case 2:  acc = opj_core<2>(partial, Wo, b, srow, brow, f32, quad); break;
        case 3:  acc = opj_core<3>(partial, Wo, b, srow, brow, f32, quad); break;
        case 4:  acc = opj_core<4>(partial, Wo, b, srow, brow, f32, quad); break;
        case 5:  acc = opj_core<5>(partial, Wo, b, srow, brow, f32, quad); break;
        case 6:  acc = opj_core<6>(partial, Wo, b, srow, brow, f32, quad); break;
        case 7:  acc = opj_core<7>(partial, Wo, b, srow, brow, f32, quad); break;
        default: acc = opj_core<8>(partial, Wo, b, srow, brow, f32, quad); break;
    }

#pragma unroll
    for (int r = 0; r < 4; ++r) {
        const size_t o = (size_t)(g0 + quad * 4 + r) * DD + ct * 16 + l16;
        if (f32) ((float*)out)[o] = acc[r];
        else     ((bf16*)out)[o]  = (bf16)acc[r];
    }
}

// ---------------------------------------------------------------------------
extern "C" void kernel_launch(void* const* d_in, const int* in_sizes, int n_in,
                              void* d_out, int out_size, void* d_ws, size_t ws_size,
                              hipStream_t stream) {
    const void* q     = d_in[0];
    const void* Wq    = d_in[1];
    const void* Wk    = d_in[2];
    const void* Wv    = d_in[3];
    const void* Wo    = d_in[4];
    const void* gamma = d_in[5];

    char* ws = (char*)d_ws;
    bf16*  qh      = (bf16*)(ws);                    // 4 MiB
    bf16*  kh      = (bf16*)(ws + 4194304);          // 4 MiB
    bf16*  vt      = (bf16*)(ws + 8388608);          // 4 MiB (tile-major)
    float* qn      = (float*)(ws + 12582912);        // 128 KiB
    float* kn      = (float*)(ws + 12713984);        // 128 KiB
    int*   flag    = (int*)  (ws + 12845056);
    bf16*  partial = (bf16*)(ws + 13631488);         // nslot x 4 MiB (bf16)

    // split-K tier by available workspace: 8 / 4 / 2 / 1 slots
    int ksh = 11;
    const size_t base = 13631488ull;
    if      (ws_size >= base + 8ull * 4194304) ksh = 8;
    else if (ws_size >= base + 4ull * 4194304) ksh = 9;
    else if (ws_size >= base + 2ull * 4194304) ksh = 10;

    const int G = 1 << (ksh - 4);
    const int n = 128 / G;                           // slot-groups
    const int perbh = G * n * (n + 1) / 2;           // active (qt,slot) per bh

    proj_rope_kernel<<<dim3(3 * BB * (SS / 16) * HH), dim3(64), 0, stream>>>(
        q, Wq, Wk, Wv, qh, kh, vt, qn, kn, flag);
    attn_kernel<<<dim3(BB * HH * perbh), dim3(64), 0, stream>>>(
        qh, kh, vt, qn, kn, gamma, partial, flag, ksh, perbh);
    outproj_kernel<<<dim3(BB * SS / 16), dim3(256), 0, stream>>>(
        partial, Wo, d_out, flag, ksh);
}

// Round 12
// 163.167 us; speedup vs baseline: 2.0962x; 1.0046x over previous
//
#include <hip/hip_runtime.h>
#include <hip/hip_bf16.h>

// Problem constants
#define BB 2
#define SS 2048
#define DD 64
#define HH 8
#define HD 512            // HH*DD
#define SCALE 0.125f      // 1/sqrt(64)

typedef __bf16 bf16;
typedef __attribute__((ext_vector_type(4))) __bf16 bf16x4;
typedef __attribute__((ext_vector_type(8))) __bf16 bf16x8;
typedef __attribute__((ext_vector_type(4))) float floatx4;

#define PSLOT 2097152     // bf16 elements per partial slot = BB*HH*SS*DD (4 MiB)

__device__ __forceinline__ floatx4 mfma16(bf16x8 a, bf16x8 b, floatx4 c) {
    return __builtin_amdgcn_mfma_f32_16x16x32_bf16(a, b, c, 0, 0, 0);
}

// v_mfma_f32_16x16x16_bf16 via inline asm (ISA-documented on gfx950).
// Hazard recognizer can't see inside asm: embedded s_nop 1 guarantees the
// >=2 wait states between VALU writes of A/B and the MFMA read.
#define PV_MFMA(ACC, A, B) \
    asm("s_nop 1\n\tv_mfma_f32_16x16x16_bf16 %0, %1, %2, %0" \
        : "+v"(ACC) : "v"(A), "v"(B))

// drain MFMA pipe before VALU reads of asm-MFMA results (16 cycles)
#define MFMA_DRAIN4(A0, A1, A2, A3) \
    asm volatile("s_nop 7\n\ts_nop 7" : "+v"(A0), "+v"(A1), "+v"(A2), "+v"(A3))

__device__ __forceinline__ bf16x8 load8(const void* base, size_t idx, int f32) {
    if (f32) {
        const float* p = (const float*)base + idx;
        const float4 a = *reinterpret_cast<const float4*>(p);
        const float4 b = *reinterpret_cast<const float4*>(p + 4);
        bf16x8 r;
        r[0] = (bf16)a.x; r[1] = (bf16)a.y; r[2] = (bf16)a.z; r[3] = (bf16)a.w;
        r[4] = (bf16)b.x; r[5] = (bf16)b.y; r[6] = (bf16)b.z; r[7] = (bf16)b.w;
        return r;
    }
    return *reinterpret_cast<const bf16x8*>((const bf16*)base + idx);
}

__device__ __forceinline__ float load1(const void* base, int idx, int f32) {
    return f32 ? ((const float*)base)[idx] : (float)((const bf16*)base)[idx];
}

// ---------------------------------------------------------------------------
// Kernel 1 (R8-validated, unchanged): QKV projection + RoPE + fp32 norms.
// Q/K swapped MFMA (C = W·q^T): row=d_local -> RoPE in-lane, 8 sincos/lane.
// V unswapped, stored TILE-MAJOR vt[bh][kt][dhi][dlo][klocal].
// ---------------------------------------------------------------------------
__global__ __launch_bounds__(64) void proj_rope_kernel(
    const void* __restrict__ q, const void* __restrict__ Wq,
    const void* __restrict__ Wk, const void* __restrict__ Wv,
    bf16* __restrict__ qh, bf16* __restrict__ kh, bf16* __restrict__ vt,
    float* __restrict__ qn, float* __restrict__ kn,
    int* __restrict__ flagw)
{
    const int lane = threadIdx.x;
    const int l16  = lane & 15;
    const int quad = lane >> 4;

    // inline dtype detection over q's first 1024 halfwords
    int hit = 0;
    const unsigned short* qu = (const unsigned short*)q;
#pragma unroll
    for (int i = 0; i < 16; ++i) {
        const unsigned short u = qu[lane + i * 64];
        if (((u >> 7) & 0xFF) >= 134) hit = 1;
    }
    const int f32 = (__ballot(hit) != 0ull) ? 1 : 0;
    if (blockIdx.x == 0 && lane == 0) *flagw = f32;

    int id = blockIdx.x;                 // ((w*BB + b)*(SS/16) + st)*HH + h
    const int h  = id % HH; id /= HH;
    const int st = id % (SS / 16); id /= (SS / 16);
    const int b  = id % BB; id /= BB;
    const int w  = id;                   // 0=q, 1=k, 2=v
    const int s0 = st * 16;

    const void* W = (w == 0) ? Wq : (w == 1) ? Wk : Wv;

    const size_t qrow = ((size_t)b * SS + s0 + l16) * DD;
    bf16x8 a0 = load8(q, qrow + quad * 8, f32);
    bf16x8 a1 = load8(q, qrow + quad * 8 + 32, f32);

    floatx4 cv[4];
#pragma unroll
    for (int t = 0; t < 4; ++t) {
        const size_t wrow = (size_t)(h * 64 + t * 16 + l16) * DD;
        bf16x8 b0 = load8(W, wrow + quad * 8, f32);
        bf16x8 b1 = load8(W, wrow + quad * 8 + 32, f32);
        floatx4 acc = {0.f, 0.f, 0.f, 0.f};
        if (w < 2) {            // swapped: C[m=d_local][n=s_local]
            acc = mfma16(b0, a0, acc);
            acc = mfma16(b1, a1, acc);
        } else {                // unswapped: C[m=s_local][n=d_local]
            acc = mfma16(a0, b0, acc);
            acc = mfma16(a1, b1, acc);
        }
        cv[t] = acc;
    }

    const size_t bh = (size_t)b * HH + h;

    if (w < 2) {
        bf16*  dst  = (w == 0) ? qh : kh;
        float* ndst = (w == 0) ? qn : kn;
        const float srowf = (float)(s0 + l16);
        float nacc = 0.f;
        bf16* drow = dst + (bh * SS + s0 + l16) * DD + quad * 4;
#pragma unroll
        for (int t = 0; t < 4; ++t) {
            const int dbase = t * 16 + quad * 4;      // even
            const float frevA = __builtin_amdgcn_exp2f(
                -(float)dbase * (13.2877123795f / 64.0f)) * 0.15915494309f;
            const float frevB = __builtin_amdgcn_exp2f(
                -(float)(dbase + 2) * (13.2877123795f / 64.0f)) * 0.15915494309f;
            float revA = srowf * frevA; revA -= floorf(revA);
            float revB = srowf * frevB; revB -= floorf(revB);
            const float snA = __builtin_amdgcn_sinf(revA);
            const float csA = __builtin_amdgcn_cosf(revA);
            const float snB = __builtin_amdgcn_sinf(revB);
            const float csB = __builtin_amdgcn_cosf(revB);
            const float x0 = cv[t][0], x1 = cv[t][1];
            const float x2 = cv[t][2], x3 = cv[t][3];
            const float r0 = x0 * csA - x1 * snA;
            const float r1 = x0 * snA + x1 * csA;
            const float r2 = x2 * csB - x3 * snB;
            const float r3 = x2 * snB + x3 * csB;
            nacc += r0 * r0 + r1 * r1 + r2 * r2 + r3 * r3;
            bf16x4 o; o[0]=(bf16)r0; o[1]=(bf16)r1; o[2]=(bf16)r2; o[3]=(bf16)r3;
            *reinterpret_cast<bf16x4*>(drow + t * 16) = o;
        }
        nacc += __shfl_xor(nacc, 16);
        nacc += __shfl_xor(nacc, 32);
        if (quad == 0) ndst[bh * SS + s0 + l16] = nacc;
    } else {
        // tile-major V: [bh][st][dhi=t][dlo=l16][klocal=quad*4+r]
        bf16* vrow = vt + ((size_t)bh * 128 + st) * 1024 + l16 * 16 + quad * 4;
#pragma unroll
        for (int t = 0; t < 4; ++t) {
            bf16x4 pv;
#pragma unroll
            for (int r = 0; r < 4; ++r) pv[r] = (bf16)cv[t][r];
            *reinterpret_cast<bf16x4*>(vrow + t * 256) = pv;
        }
    }
}

// ---------------------------------------------------------------------------
// Kernel 2: R8 attn semantics (single 16-query tile per wave, R8 masks/grid/
// epilogue — passed twice at 6.1e-4) with ONE change: ping-pong software
// pipeline, depth-2 K/kn prefetch (stage A / stage B), no register ring moves.
// The chunk body is a macro so all expansions share one audited mask impl.
// Plain __launch_bounds__(64) — (64,N) caps VGPRs and spills (R7: 628 MB).
// ---------------------------------------------------------------------------
__global__ __launch_bounds__(64) void attn_kernel(
    const bf16* __restrict__ qh, const bf16* __restrict__ kh,
    const bf16* __restrict__ vt, const float* __restrict__ qn,
    const float* __restrict__ kn, const void* __restrict__ gamma,
    bf16* __restrict__ partial, const int* __restrict__ flagp,
    int ksh, int perbh)
{
    const int f32  = *flagp;
    const int lane = threadIdx.x;
    const int l16  = lane & 15;
    const int quad = lane >> 4;

    // compacted decode (R8): group g has G qt-values x (g+1) slots, G=2^(ksh-4)
    const int bh = blockIdx.x / perbh;
    int r = blockIdx.x - bh * perbh;
    const int G = 1 << (ksh - 4);
    int g = 0;
    while (r >= G * (g + 1)) { r -= G * (g + 1); ++g; }
    const int slot = r >> (ksh - 4);
    const int qt   = g * G + (r & (G - 1));
    const int s0   = qt * 16;
    const int tb   = slot << ksh;
    if (tb > s0 + 15) return;
    const int te   = min(tb + (1 << ksh), s0 + 16);
    const int nch  = (te - tb + 31) >> 5;   // 32-key chunks, tail masked
    const int h    = bh & 7;

    const float cc = load1(gamma, h, f32) * SCALE * 1.4426950408889634f;

    const bf16* qbase = qh + ((size_t)bh * SS + s0 + l16) * DD;
    bf16x8 aq0 = *reinterpret_cast<const bf16x8*>(qbase + quad * 8);
    bf16x8 aq1 = *reinterpret_cast<const bf16x8*>(qbase + quad * 8 + 32);
    const float qn_l = qn[(size_t)bh * SS + s0 + l16];

    floatx4 acc0 = {0.f,0.f,0.f,0.f}, acc1 = {0.f,0.f,0.f,0.f};
    floatx4 acc2 = {0.f,0.f,0.f,0.f}, acc3 = {0.f,0.f,0.f,0.f};

    const bf16*  kp    = kh + ((size_t)bh * SS + l16) * DD;   // + key*DD
    const float* knp   = kn + (size_t)bh * SS + quad * 4;     // + key
    const bf16*  vbase = vt + (size_t)bh * 131072 + l16 * 16 + quad * 4;

    bf16x8 A0, A1, A2, A3; float4 An0, An1;    // stage A
    bf16x8 B0, B1, B2, B3; float4 Bn0, Bn1;    // stage B

#define LOADK(K0, K1, K2, K3, N0, N1, T) do {                                   \
    K0 = *reinterpret_cast<const bf16x8*>(kp + (size_t)(T) * DD + quad * 8);    \
    K1 = *reinterpret_cast<const bf16x8*>(kp + (size_t)(T) * DD + quad * 8 + 32);\
    K2 = *reinterpret_cast<const bf16x8*>(kp + (size_t)((T) + 16) * DD + quad * 8);\
    K3 = *reinterpret_cast<const bf16x8*>(kp + (size_t)((T) + 16) * DD + quad * 8 + 32);\
    N0 = *reinterpret_cast<const float4*>(knp + (T));                           \
    N1 = *reinterpret_cast<const float4*>(knp + (T) + 16);                      \
} while (0)

#define CHUNK(K0, K1, K2, K3, N0, N1, T) do {                                   \
    const int t0_ = (T);                                                        \
    const bf16* v0p = vbase + (size_t)(t0_ >> 4) * 1024;                        \
    bf16x4 v00 = *reinterpret_cast<const bf16x4*>(v0p);                         \
    bf16x4 v01 = *reinterpret_cast<const bf16x4*>(v0p + 256);                   \
    bf16x4 v02 = *reinterpret_cast<const bf16x4*>(v0p + 512);                   \
    bf16x4 v03 = *reinterpret_cast<const bf16x4*>(v0p + 768);                   \
    bf16x4 v10 = *reinterpret_cast<const bf16x4*>(v0p + 1024);                  \
    bf16x4 v11 = *reinterpret_cast<const bf16x4*>(v0p + 1280);                  \
    bf16x4 v12 = *reinterpret_cast<const bf16x4*>(v0p + 1536);                  \
    bf16x4 v13 = *reinterpret_cast<const bf16x4*>(v0p + 1792);                  \
    floatx4 z0 = {0.f,0.f,0.f,0.f};                                             \
    z0 = mfma16(K0, aq0, z0);                                                   \
    z0 = mfma16(K1, aq1, z0);                                                   \
    floatx4 z1 = {0.f,0.f,0.f,0.f};                                             \
    z1 = mfma16(K2, aq0, z1);                                                   \
    z1 = mfma16(K3, aq1, z1);                                                   \
    const float* k0_ = (const float*)&(N0);                                     \
    const float* k1_ = (const float*)&(N1);                                     \
    bf16x4 p0, p1;                                                              \
    if (t0_ + 31 <= s0) {                                                       \
        _Pragma("unroll")                                                       \
        for (int i = 0; i < 4; ++i) {                                           \
            float rawA = fmaf(-2.f, z0[i], qn_l + k0_[i]);                      \
            float rawB = fmaf(-2.f, z1[i], qn_l + k1_[i]);                      \
            p0[i] = (bf16)__builtin_amdgcn_exp2f(fminf(-cc * rawA, 0.f));       \
            p1[i] = (bf16)__builtin_amdgcn_exp2f(fminf(-cc * rawB, 0.f));       \
        }                                                                       \
    } else {                                                                    \
        const int dq0 = s0 + l16 - t0_ - quad * 4;                              \
        const int dq1 = dq0 - 16;                                               \
        _Pragma("unroll")                                                       \
        for (int i = 0; i < 4; ++i) {                                           \
            float rawA = fmaf(-2.f, z0[i], qn_l + k0_[i]);                      \
            float rawB = fmaf(-2.f, z1[i], qn_l + k1_[i]);                      \
            float eA = __builtin_amdgcn_exp2f(fminf(-cc * rawA, 0.f));          \
            float eB = __builtin_amdgcn_exp2f(fminf(-cc * rawB, 0.f));          \
            p0[i] = (bf16)((i <= dq0) ? eA : 0.f);                              \
            p1[i] = (bf16)((i <= dq1) ? eB : 0.f);                              \
        }                                                                       \
    }                                                                           \
    PV_MFMA(acc0, v00, p0);                                                     \
    PV_MFMA(acc1, v01, p0);                                                     \
    PV_MFMA(acc2, v02, p0);                                                     \
    PV_MFMA(acc3, v03, p0);                                                     \
    PV_MFMA(acc0, v10, p1);                                                     \
    PV_MFMA(acc1, v11, p1);                                                     \
    PV_MFMA(acc2, v12, p1);                                                     \
    PV_MFMA(acc3, v13, p1);                                                     \
} while (0)

    LOADK(A0, A1, A2, A3, An0, An1, tb);
    if (nch > 1) LOADK(B0, B1, B2, B3, Bn0, Bn1, tb + 32);

    int c = 0, t0 = tb;
    for (; c + 1 < nch; c += 2, t0 += 64) {
        CHUNK(A0, A1, A2, A3, An0, An1, t0);
        if (c + 2 < nch) LOADK(A0, A1, A2, A3, An0, An1, t0 + 64);
        CHUNK(B0, B1, B2, B3, Bn0, Bn1, t0 + 32);
        if (c + 3 < nch) LOADK(B0, B1, B2, B3, Bn0, Bn1, t0 + 96);
    }
    if (c < nch) CHUNK(A0, A1, A2, A3, An0, An1, t0);

#undef CHUNK
#undef LOADK

    MFMA_DRAIN4(acc0, acc1, acc2, acc3);

    // O^T C-frag: col=query=l16, row=d_local=quad*4+r -> bf16x4 per nb
    bf16* pb = partial + (size_t)slot * PSLOT
             + ((size_t)bh * SS + s0 + l16) * DD + quad * 4;
    bf16x4 o;
#define STORE4(PTR, ACC) \
    o[0]=(bf16)(ACC)[0]; o[1]=(bf16)(ACC)[1]; o[2]=(bf16)(ACC)[2]; o[3]=(bf16)(ACC)[3]; \
    *reinterpret_cast<bf16x4*>(PTR) = o;
    STORE4(pb +  0, acc0)
    STORE4(pb + 16, acc1)
    STORE4(pb + 32, acc2)
    STORE4(pb + 48, acc3)
#undef STORE4
#undef STORE4
}

// ---------------------------------------------------------------------------
// Kernel 3 (R8-validated, unchanged): fused split-K reduce + output proj.
// ---------------------------------------------------------------------------
template <int NACT>
__device__ __forceinline__ floatx4 opj_core(const bf16* __restrict__ partial,
                                            const void* __restrict__ Wo,
                                            int b, int srow, size_t brow,
                                            int f32, int quad) {
    floatx4 acc = {0.f, 0.f, 0.f, 0.f};
#pragma unroll 4
    for (int kk = 0; kk < HD; kk += 32) {
        const int h  = kk >> 6;
        const int d0 = (kk & 63) + quad * 8;
        const bf16* ap = partial + (((size_t)(b * 8 + h)) * SS + srow) * 64 + d0;
        bf16x8 v0 = *reinterpret_cast<const bf16x8*>(ap);
        float u[8];
#pragma unroll
        for (int i = 0; i < 8; ++i) u[i] = (float)v0[i];
#pragma unroll
        for (int s = 1; s < NACT; ++s) {
            bf16x8 vs = *reinterpret_cast<const bf16x8*>(ap + (size_t)s * PSLOT);
#pragma unroll
            for (int i = 0; i < 8; ++i) u[i] += (float)vs[i];
        }
        bf16x8 a;
#pragma unroll
        for (int i = 0; i < 8; ++i) a[i] = (bf16)u[i];
        bf16x8 w = load8(Wo, brow + kk, f32);
        acc = mfma16(a, w, acc);
    }
    return acc;
}

__global__ __launch_bounds__(256) void outproj_kernel(
    const bf16* __restrict__ partial, const void* __restrict__ Wo,
    void* __restrict__ out, const int* __restrict__ flagp, int ksh)
{
    const int f32  = *flagp;
    const int ct   = threadIdx.x >> 6;
    const int lane = threadIdx.x & 63;
    const int l16  = lane & 15;
    const int quad = lane >> 4;

    const int g0   = blockIdx.x * 16;          // global row (b*SS + s)
    const int b    = g0 >> 11;
    const int s0   = g0 & (SS - 1);
    const int nact = (s0 >> ksh) + 1;
    const int srow = s0 + l16;
    const size_t brow = (size_t)(ct * 16 + l16) * HD + quad * 8;

    floatx4 acc;
    switch (nact) {
        case 1:  acc = opj_core<1>(partial, Wo, b, srow, brow, f32, quad); break;
        case 2:  acc = opj_core<2>(partial, Wo, b, srow, brow, f32, quad); break;
        case 3:  acc = opj_core<3>(partial, Wo, b, srow, brow, f32, quad); break;
        case 4:  acc = opj_core<4>(partial, Wo, b, srow, brow, f32, quad); break;
        case 5:  acc = opj_core<5>(partial, Wo, b, srow, brow, f32, quad); break;
        case 6:  acc = opj_core<6>(partial, Wo, b, srow, brow, f32, quad); break;
        case 7:  acc = opj_core<7>(partial, Wo, b, srow, brow, f32, quad); break;
        default: acc = opj_core<8>(partial, Wo, b, srow, brow, f32, quad); break;
    }

#pragma unroll
    for (int r = 0; r < 4; ++r) {
        const size_t o = (size_t)(g0 + quad * 4 + r) * DD + ct * 16 + l16;
        if (f32) ((float*)out)[o] = acc[r];
        else     ((bf16*)out)[o]  = (bf16)acc[r];
    }
}

// ---------------------------------------------------------------------------
extern "C" void kernel_launch(void* const* d_in, const int* in_sizes, int n_in,
                              void* d_out, int out_size, void* d_ws, size_t ws_size,
                              hipStream_t stream) {
    const void* q     = d_in[0];
    const void* Wq    = d_in[1];
    const void* Wk    = d_in[2];
    const void* Wv    = d_in[3];
    const void* Wo    = d_in[4];
    const void* gamma = d_in[5];

    char* ws = (char*)d_ws;
    bf16*  qh      = (bf16*)(ws);                    // 4 MiB
    bf16*  kh      = (bf16*)(ws + 4194304);          // 4 MiB
    bf16*  vt      = (bf16*)(ws + 8388608);          // 4 MiB (tile-major)
    float* qn      = (float*)(ws + 12582912);        // 128 KiB
    float* kn      = (float*)(ws + 12713984);        // 128 KiB
    int*   flag    = (int*)  (ws + 12845056);
    bf16*  partial = (bf16*)(ws + 13631488);         // nslot x 4 MiB (bf16)

    // split-K tier by available workspace: 8 / 4 / 2 / 1 slots
    int ksh = 11;
    const size_t base = 13631488ull;
    if      (ws_size >= base + 8ull * 4194304) ksh = 8;
    else if (ws_size >= base + 4ull * 4194304) ksh = 9;
    else if (ws_size >= base + 2ull * 4194304) ksh = 10;

    const int G = 1 << (ksh - 4);
    const int n = 128 / G;                           // slot-groups
    const int perbh = G * n * (n + 1) / 2;           // active (qt,slot) per bh

    proj_rope_kernel<<<dim3(3 * BB * (SS / 16) * HH), dim3(64), 0, stream>>>(
        q, Wq, Wk, Wv, qh, kh, vt, qn, kn, flag);
    attn_kernel<<<dim3(BB * HH * perbh), dim3(64), 0, stream>>>(
        qh, kh, vt, qn, kn, gamma, partial, flag, ksh, perbh);
    outproj_kernel<<<dim3(BB * SS / 16), dim3(256), 0, stream>>>(
        partial, Wo, d_out, flag, ksh);
}

// Round 13
// 162.281 us; speedup vs baseline: 2.1076x; 1.0055x over previous
//
#include <hip/hip_runtime.h>
#include <hip/hip_bf16.h>

// Problem constants
#define BB 2
#define SS 2048
#define DD 64
#define HH 8
#define HD 512            // HH*DD
#define SCALE 0.125f      // 1/sqrt(64)

typedef __bf16 bf16;
typedef __attribute__((ext_vector_type(4))) __bf16 bf16x4;
typedef __attribute__((ext_vector_type(8))) __bf16 bf16x8;
typedef __attribute__((ext_vector_type(4))) float floatx4;

#define PSLOT 2097152     // bf16 elements per partial slot = BB*HH*SS*DD (4 MiB)

__device__ __forceinline__ floatx4 mfma16(bf16x8 a, bf16x8 b, floatx4 c) {
    return __builtin_amdgcn_mfma_f32_16x16x32_bf16(a, b, c, 0, 0, 0);
}

// v_mfma_f32_16x16x16_bf16 via inline asm (ISA-documented on gfx950).
// Hazard recognizer can't see inside asm: embedded s_nop 1 guarantees the
// >=2 wait states between VALU writes of A/B and the MFMA read.
#define PV_MFMA(ACC, A, B) \
    asm("s_nop 1\n\tv_mfma_f32_16x16x16_bf16 %0, %1, %2, %0" \
        : "+v"(ACC) : "v"(A), "v"(B))

// drain MFMA pipe before VALU reads of asm-MFMA results (16 cycles)
#define MFMA_DRAIN4(A0, A1, A2, A3) \
    asm volatile("s_nop 7\n\ts_nop 7" : "+v"(A0), "+v"(A1), "+v"(A2), "+v"(A3))

__device__ __forceinline__ bf16x8 load8(const void* base, size_t idx, int f32) {
    if (f32) {
        const float* p = (const float*)base + idx;
        const float4 a = *reinterpret_cast<const float4*>(p);
        const float4 b = *reinterpret_cast<const float4*>(p + 4);
        bf16x8 r;
        r[0] = (bf16)a.x; r[1] = (bf16)a.y; r[2] = (bf16)a.z; r[3] = (bf16)a.w;
        r[4] = (bf16)b.x; r[5] = (bf16)b.y; r[6] = (bf16)b.z; r[7] = (bf16)b.w;
        return r;
    }
    return *reinterpret_cast<const bf16x8*>((const bf16*)base + idx);
}

__device__ __forceinline__ float load1(const void* base, int idx, int f32) {
    return f32 ? ((const float*)base)[idx] : (float)((const bf16*)base)[idx];
}

// ---------------------------------------------------------------------------
// Kernel 1 (R8/R12-validated math, 4 waves/block): QKV proj + RoPE + norms.
// Waves are fully independent; wave w of block b handles work-id b*4+w —
// single-wave workgroups were capping blocks/CU residency (occupancy 32%).
// ---------------------------------------------------------------------------
__global__ __launch_bounds__(256) void proj_rope_kernel(
    const void* __restrict__ q, const void* __restrict__ Wq,
    const void* __restrict__ Wk, const void* __restrict__ Wv,
    bf16* __restrict__ qh, bf16* __restrict__ kh, bf16* __restrict__ vt,
    float* __restrict__ qn, float* __restrict__ kn,
    int* __restrict__ flagw)
{
    const int lane = threadIdx.x & 63;
    const int wid  = blockIdx.x * 4 + (threadIdx.x >> 6);
    if (wid >= 3 * BB * (SS / 16) * HH) return;
    const int l16  = lane & 15;
    const int quad = lane >> 4;

    // inline dtype detection over q's first 1024 halfwords (per-wave ballot)
    int hit = 0;
    const unsigned short* qu = (const unsigned short*)q;
#pragma unroll
    for (int i = 0; i < 16; ++i) {
        const unsigned short u = qu[lane + i * 64];
        if (((u >> 7) & 0xFF) >= 134) hit = 1;
    }
    const int f32 = (__ballot(hit) != 0ull) ? 1 : 0;
    if (wid == 0 && lane == 0) *flagw = f32;

    int id = wid;                        // ((w*BB + b)*(SS/16) + st)*HH + h
    const int h  = id % HH; id /= HH;
    const int st = id % (SS / 16); id /= (SS / 16);
    const int b  = id % BB; id /= BB;
    const int w  = id;                   // 0=q, 1=k, 2=v
    const int s0 = st * 16;

    const void* W = (w == 0) ? Wq : (w == 1) ? Wk : Wv;

    const size_t qrow = ((size_t)b * SS + s0 + l16) * DD;
    bf16x8 a0 = load8(q, qrow + quad * 8, f32);
    bf16x8 a1 = load8(q, qrow + quad * 8 + 32, f32);

    floatx4 cv[4];
#pragma unroll
    for (int t = 0; t < 4; ++t) {
        const size_t wrow = (size_t)(h * 64 + t * 16 + l16) * DD;
        bf16x8 b0 = load8(W, wrow + quad * 8, f32);
        bf16x8 b1 = load8(W, wrow + quad * 8 + 32, f32);
        floatx4 acc = {0.f, 0.f, 0.f, 0.f};
        if (w < 2) {            // swapped: C[m=d_local][n=s_local]
            acc = mfma16(b0, a0, acc);
            acc = mfma16(b1, a1, acc);
        } else {                // unswapped: C[m=s_local][n=d_local]
            acc = mfma16(a0, b0, acc);
            acc = mfma16(a1, b1, acc);
        }
        cv[t] = acc;
    }

    const size_t bh = (size_t)b * HH + h;

    if (w < 2) {
        bf16*  dst  = (w == 0) ? qh : kh;
        float* ndst = (w == 0) ? qn : kn;
        const float srowf = (float)(s0 + l16);
        float nacc = 0.f;
        bf16* drow = dst + (bh * SS + s0 + l16) * DD + quad * 4;
#pragma unroll
        for (int t = 0; t < 4; ++t) {
            const int dbase = t * 16 + quad * 4;      // even
            const float frevA = __builtin_amdgcn_exp2f(
                -(float)dbase * (13.2877123795f / 64.0f)) * 0.15915494309f;
            const float frevB = __builtin_amdgcn_exp2f(
                -(float)(dbase + 2) * (13.2877123795f / 64.0f)) * 0.15915494309f;
            float revA = srowf * frevA; revA -= floorf(revA);
            float revB = srowf * frevB; revB -= floorf(revB);
            const float snA = __builtin_amdgcn_sinf(revA);
            const float csA = __builtin_amdgcn_cosf(revA);
            const float snB = __builtin_amdgcn_sinf(revB);
            const float csB = __builtin_amdgcn_cosf(revB);
            const float x0 = cv[t][0], x1 = cv[t][1];
            const float x2 = cv[t][2], x3 = cv[t][3];
            const float r0 = x0 * csA - x1 * snA;
            const float r1 = x0 * snA + x1 * csA;
            const float r2 = x2 * csB - x3 * snB;
            const float r3 = x2 * snB + x3 * csB;
            nacc += r0 * r0 + r1 * r1 + r2 * r2 + r3 * r3;
            bf16x4 o; o[0]=(bf16)r0; o[1]=(bf16)r1; o[2]=(bf16)r2; o[3]=(bf16)r3;
            *reinterpret_cast<bf16x4*>(drow + t * 16) = o;
        }
        nacc += __shfl_xor(nacc, 16);
        nacc += __shfl_xor(nacc, 32);
        if (quad == 0) ndst[bh * SS + s0 + l16] = nacc;
    } else {
        // tile-major V: [bh][st][dhi=t][dlo=l16][klocal=quad*4+r]
        bf16* vrow = vt + ((size_t)bh * 128 + st) * 1024 + l16 * 16 + quad * 4;
#pragma unroll
        for (int t = 0; t < 4; ++t) {
            bf16x4 pv;
#pragma unroll
            for (int r = 0; r < 4; ++r) pv[r] = (bf16)cv[t][r];
            *reinterpret_cast<bf16x4*>(vrow + t * 256) = pv;
        }
    }
}

// ---------------------------------------------------------------------------
// Kernel 2: R12 attn semantics (PASSED at 6.1e-4) packed 4 INDEPENDENT WAVES
// per 256-thread block. Per-wave code identical to R12: single 16-query tile,
// split-K compacted grid, depth-2 ping-pong K/kn prefetch, register-direct
// S^T->PV. No barriers, no LDS, no inter-wave sharing. 60 VGPR x 4-wave
// blocks -> 8 blocks/CU = 32 waves/CU possible (was ~10 with 1-wave blocks).
// ---------------------------------------------------------------------------
__global__ __launch_bounds__(256) void attn_kernel(
    const bf16* __restrict__ qh, const bf16* __restrict__ kh,
    const bf16* __restrict__ vt, const float* __restrict__ qn,
    const float* __restrict__ kn, const void* __restrict__ gamma,
    bf16* __restrict__ partial, const int* __restrict__ flagp,
    int ksh, int perbh, int nwork)
{
    const int wid = blockIdx.x * 4 + (threadIdx.x >> 6);
    if (wid >= nwork) return;
    const int f32  = *flagp;
    const int lane = threadIdx.x & 63;
    const int l16  = lane & 15;
    const int quad = lane >> 4;

    // compacted decode (R8): group g has G qt-values x (g+1) slots, G=2^(ksh-4)
    const int bh = wid / perbh;
    int r = wid - bh * perbh;
    const int G = 1 << (ksh - 4);
    int g = 0;
    while (r >= G * (g + 1)) { r -= G * (g + 1); ++g; }
    const int slot = r >> (ksh - 4);
    const int qt   = g * G + (r & (G - 1));
    const int s0   = qt * 16;
    const int tb   = slot << ksh;
    if (tb > s0 + 15) return;
    const int te   = min(tb + (1 << ksh), s0 + 16);
    const int nch  = (te - tb + 31) >> 5;   // 32-key chunks, tail masked
    const int h    = bh & 7;

    const float cc = load1(gamma, h, f32) * SCALE * 1.4426950408889634f;

    const bf16* qbase = qh + ((size_t)bh * SS + s0 + l16) * DD;
    bf16x8 aq0 = *reinterpret_cast<const bf16x8*>(qbase + quad * 8);
    bf16x8 aq1 = *reinterpret_cast<const bf16x8*>(qbase + quad * 8 + 32);
    const float qn_l = qn[(size_t)bh * SS + s0 + l16];

    floatx4 acc0 = {0.f,0.f,0.f,0.f}, acc1 = {0.f,0.f,0.f,0.f};
    floatx4 acc2 = {0.f,0.f,0.f,0.f}, acc3 = {0.f,0.f,0.f,0.f};

    const bf16*  kp    = kh + ((size_t)bh * SS + l16) * DD;   // + key*DD
    const float* knp   = kn + (size_t)bh * SS + quad * 4;     // + key
    const bf16*  vbase = vt + (size_t)bh * 131072 + l16 * 16 + quad * 4;

    bf16x8 A0, A1, A2, A3; float4 An0, An1;    // stage A
    bf16x8 B0, B1, B2, B3; float4 Bn0, Bn1;    // stage B

#define LOADK(K0, K1, K2, K3, N0, N1, T) do {                                   \
    K0 = *reinterpret_cast<const bf16x8*>(kp + (size_t)(T) * DD + quad * 8);    \
    K1 = *reinterpret_cast<const bf16x8*>(kp + (size_t)(T) * DD + quad * 8 + 32);\
    K2 = *reinterpret_cast<const bf16x8*>(kp + (size_t)((T) + 16) * DD + quad * 8);\
    K3 = *reinterpret_cast<const bf16x8*>(kp + (size_t)((T) + 16) * DD + quad * 8 + 32);\
    N0 = *reinterpret_cast<const float4*>(knp + (T));                           \
    N1 = *reinterpret_cast<const float4*>(knp + (T) + 16);                      \
} while (0)

#define CHUNK(K0, K1, K2, K3, N0, N1, T) do {                                   \
    const int t0_ = (T);                                                        \
    const bf16* v0p = vbase + (size_t)(t0_ >> 4) * 1024;                        \
    bf16x4 v00 = *reinterpret_cast<const bf16x4*>(v0p);                         \
    bf16x4 v01 = *reinterpret_cast<const bf16x4*>(v0p + 256);                   \
    bf16x4 v02 = *reinterpret_cast<const bf16x4*>(v0p + 512);                   \
    bf16x4 v03 = *reinterpret_cast<const bf16x4*>(v0p + 768);                   \
    bf16x4 v10 = *reinterpret_cast<const bf16x4*>(v0p + 1024);                  \
    bf16x4 v11 = *reinterpret_cast<const bf16x4*>(v0p + 1280);                  \
    bf16x4 v12 = *reinterpret_cast<const bf16x4*>(v0p + 1536);                  \
    bf16x4 v13 = *reinterpret_cast<const bf16x4*>(v0p + 1792);                  \
    floatx4 z0 = {0.f,0.f,0.f,0.f};                                             \
    z0 = mfma16(K0, aq0, z0);                                                   \
    z0 = mfma16(K1, aq1, z0);                                                   \
    floatx4 z1 = {0.f,0.f,0.f,0.f};                                             \
    z1 = mfma16(K2, aq0, z1);                                                   \
    z1 = mfma16(K3, aq1, z1);                                                   \
    const float* k0_ = (const float*)&(N0);                                     \
    const float* k1_ = (const float*)&(N1);                                     \
    bf16x4 p0, p1;                                                              \
    if (t0_ + 31 <= s0) {                                                       \
        _Pragma("unroll")                                                       \
        for (int i = 0; i < 4; ++i) {                                           \
            float rawA = fmaf(-2.f, z0[i], qn_l + k0_[i]);                      \
            float rawB = fmaf(-2.f, z1[i], qn_l + k1_[i]);                      \
            p0[i] = (bf16)__builtin_amdgcn_exp2f(fminf(-cc * rawA, 0.f));       \
            p1[i] = (bf16)__builtin_amdgcn_exp2f(fminf(-cc * rawB, 0.f));       \
        }                                                                       \
    } else {                                                                    \
        const int dq0 = s0 + l16 - t0_ - quad * 4;                              \
        const int dq1 = dq0 - 16;                                               \
        _Pragma("unroll")                                                       \
        for (int i = 0; i < 4; ++i) {                                           \
            float rawA = fmaf(-2.f, z0[i], qn_l + k0_[i]);                      \
            float rawB = fmaf(-2.f, z1[i], qn_l + k1_[i]);                      \
            float eA = __builtin_amdgcn_exp2f(fminf(-cc * rawA, 0.f));          \
            float eB = __builtin_amdgcn_exp2f(fminf(-cc * rawB, 0.f));          \
            p0[i] = (bf16)((i <= dq0) ? eA : 0.f);                              \
            p1[i] = (bf16)((i <= dq1) ? eB : 0.f);                              \
        }                                                                       \
    }                                                                           \
    PV_MFMA(acc0, v00, p0);                                                     \
    PV_MFMA(acc1, v01, p0);                                                     \
    PV_MFMA(acc2, v02, p0);                                                     \
    PV_MFMA(acc3, v03, p0);                                                     \
    PV_MFMA(acc0, v10, p1);                                                     \
    PV_MFMA(acc1, v11, p1);                                                     \
    PV_MFMA(acc2, v12, p1);                                                     \
    PV_MFMA(acc3, v13, p1);                                                     \
} while (0)

    LOADK(A0, A1, A2, A3, An0, An1, tb);
    if (nch > 1) LOADK(B0, B1, B2, B3, Bn0, Bn1, tb + 32);

    int c = 0, t0 = tb;
    for (; c + 1 < nch; c += 2, t0 += 64) {
        CHUNK(A0, A1, A2, A3, An0, An1, t0);
        if (c + 2 < nch) LOADK(A0, A1, A2, A3, An0, An1, t0 + 64);
        CHUNK(B0, B1, B2, B3, Bn0, Bn1, t0 + 32);
        if (c + 3 < nch) LOADK(B0, B1, B2, B3, Bn0, Bn1, t0 + 96);
    }
    if (c < nch) CHUNK(A0, A1, A2, A3, An0, An1, t0);

#undef CHUNK
#undef LOADK

    MFMA_DRAIN4(acc0, acc1, acc2, acc3);

    // O^T C-frag: col=query=l16, row=d_local=quad*4+r -> bf16x4 per nb
    bf16* pb = partial + (size_t)slot * PSLOT
             + ((size_t)bh * SS + s0 + l16) * DD + quad * 4;
    bf16x4 o;
#define STORE4(PTR, ACC) \
    o[0]=(bf16)(ACC)[0]; o[1]=(bf16)(ACC)[1]; o[2]=(bf16)(ACC)[2]; o[3]=(bf16)(ACC)[3]; \
    *reinterpret_cast<bf16x4*>(PTR) = o;
    STORE4(pb +  0, acc0)
    STORE4(pb + 16, acc1)
    STORE4(pb + 32, acc2)
    STORE4(pb + 48, acc3)
#undef STORE4
}

// ---------------------------------------------------------------------------
// Kernel 3 (R8/R12-validated, unchanged): fused split-K reduce + output proj.
// ---------------------------------------------------------------------------
template <int NACT>
__device__ __forceinline__ floatx4 opj_core(const bf16* __restrict__ partial,
                                            const void* __restrict__ Wo,
                                            int b, int srow, size_t brow,
                                            int f32, int quad) {
    floatx4 acc = {0.f, 0.f, 0.f, 0.f};
#pragma unroll 4
    for (int kk = 0; kk < HD; kk += 32) {
        const int h  = kk >> 6;
        const int d0 = (kk & 63) + quad * 8;
        const bf16* ap = partial + (((size_t)(b * 8 + h)) * SS + srow) * 64 + d0;
        bf16x8 v0 = *reinterpret_cast<const bf16x8*>(ap);
        float u[8];
#pragma unroll
        for (int i = 0; i < 8; ++i) u[i] = (float)v0[i];
#pragma unroll
        for (int s = 1; s < NACT; ++s) {
            bf16x8 vs = *reinterpret_cast<const bf16x8*>(ap + (size_t)s * PSLOT);
#pragma unroll
            for (int i = 0; i < 8; ++i) u[i] += (float)vs[i];
        }
        bf16x8 a;
#pragma unroll
        for (int i = 0; i < 8; ++i) a[i] = (bf16)u[i];
        bf16x8 w = load8(Wo, brow + kk, f32);
        acc = mfma16(a, w, acc);
    }
    return acc;
}

__global__ __launch_bounds__(256) void outproj_kernel(
    const bf16* __restrict__ partial, const void* __restrict__ Wo,
    void* __restrict__ out, const int* __restrict__ flagp, int ksh)
{
    const int f32  = *flagp;
    const int ct   = threadIdx.x >> 6;
    const int lane = threadIdx.x & 63;
    const int l16  = lane & 15;
    const int quad = lane >> 4;

    const int g0   = blockIdx.x * 16;          // global row (b*SS + s)
    const int b    = g0 >> 11;
    const int s0   = g0 & (SS - 1);
    const int nact = (s0 >> ksh) + 1;
    const int srow = s0 + l16;
    const size_t brow = (size_t)(ct * 16 + l16) * HD + quad * 8;

    floatx4 acc;
    switch (nact) {
        case 1:  acc = opj_core<1>(partial, Wo, b, srow, brow, f32, quad); break;
        case 2:  acc = opj_core<2>(partial, Wo, b, srow, brow, f32, quad); break;
        case 3:  acc = opj_core<3>(partial, Wo, b, srow, brow, f32, quad); break;
        case 4:  acc = opj_core<4>(partial, Wo, b, srow, brow, f32, quad); break;
        case 5:  acc = opj_core<5>(partial, Wo, b, srow, brow, f32, quad); break;
        case 6:  acc = opj_core<6>(partial, Wo, b, srow, brow, f32, quad); break;
        case 7:  acc = opj_core<7>(partial, Wo, b, srow, brow, f32, quad); break;
        default: acc = opj_core<8>(partial, Wo, b, srow, brow, f32, quad); break;
    }

#pragma unroll
    for (int r = 0; r < 4; ++r) {
        const size_t o = (size_t)(g0 + quad * 4 + r) * DD + ct * 16 + l16;
        if (f32) ((float*)out)[o] = acc[r];
        else     ((bf16*)out)[o]  = (bf16)acc[r];
    }
}

// ---------------------------------------------------------------------------
extern "C" void kernel_launch(void* const* d_in, const int* in_sizes, int n_in,
                              void* d_out, int out_size, void* d_ws, size_t ws_size,
                              hipStream_t stream) {
    const void* q     = d_in[0];
    const void* Wq    = d_in[1];
    const void* Wk    = d_in[2];
    const void* Wv    = d_in[3];
    const void* Wo    = d_in[4];
    const void* gamma = d_in[5];

    char* ws = (char*)d_ws;
    bf16*  qh      = (bf16*)(ws);                    // 4 MiB
    bf16*  kh      = (bf16*)(ws + 4194304);          // 4 MiB
    bf16*  vt      = (bf16*)(ws + 8388608);          // 4 MiB (tile-major)
    float* qn      = (float*)(ws + 12582912);        // 128 KiB
    float* kn      = (float*)(ws + 12713984);        // 128 KiB
    int*   flag    = (int*)  (ws + 12845056);
    bf16*  partial = (bf16*)(ws + 13631488);         // nslot x 4 MiB (bf16)

    // split-K tier by available workspace: 8 / 4 / 2 / 1 slots
    int ksh = 11;
    const size_t base = 13631488ull;
    if      (ws_size >= base + 8ull * 4194304) ksh = 8;
    else if (ws_size >= base + 4ull * 4194304) ksh = 9;
    else if (ws_size >= base + 2ull * 4194304) ksh = 10;

    const int G = 1 << (ksh - 4);
    const int n = 128 / G;                           // slot-groups
    const int perbh = G * n * (n + 1) / 2;           // active (qt,slot) per bh
    const int nwork = BB * HH * perbh;

    const int nproj = 3 * BB * (SS / 16) * HH;       // 6144 proj work items
    proj_rope_kernel<<<dim3((nproj + 3) / 4), dim3(256), 0, stream>>>(
        q, Wq, Wk, Wv, qh, kh, vt, qn, kn, flag);
    attn_kernel<<<dim3((nwork + 3) / 4), dim3(256), 0, stream>>>(
        qh, kh, vt, qn, kn, gamma, partial, flag, ksh, perbh, nwork);
    outproj_kernel<<<dim3(BB * SS / 16), dim3(256), 0, stream>>>(
        partial, Wo, d_out, flag, ksh);
}